// Round 9
// baseline (412.824 us; speedup 1.0000x reference)
//
#include <hip/hip_runtime.h>
#include <hip/hip_fp16.h>
#include <math.h>

namespace {
constexpr int NCOL = 384, NROW = 64, NVIEW = 16, NSAMP = 256;
constexpr float DET_U = 1.2f, DET_V = 1.2f;
constexpr float ISO = 500.0f, SDD = 1000.0f;
constexpr double SQRT3 = 1.7320508075688772;
constexpr float DT = (float)SQRT3;                          // RAY_LEN / NSAMP
constexpr float T0 = (float)(500.0 - SQRT3 * 256.0 * 0.5); // ISO - RAY_LEN/2
constexpr size_t VOL_N = 256u * 256u * 256u;               // 16.7M voxels
}

// t-interval where p0 + t*d lies in [LO, HI]; empty -> [1e30, -1e30]
__device__ __forceinline__ void axis_interval(float p0, float d, float LO, float HI,
                                              float& tlo, float& thi) {
    if (fabsf(d) < 1e-7f) {
        if (p0 < LO || p0 > HI) { tlo = 1e30f; thi = -1e30f; }
        else                    { tlo = -1e30f; thi = 1e30f; }
    } else {
        const float r = 1.0f / d;
        const float t1 = (LO - p0) * r, t2 = (HI - p0) * r;
        tlo = fminf(t1, t2); thi = fmaxf(t1, t2);
    }
}

// general (shell) sample on the ORIGINAL fp32 volume: per-corner check
__device__ __forceinline__ float sample_shell(const float* __restrict__ vol,
                                              float vx, float vy, float vz) {
    if (!(vx > -1.0f && vx < 256.0f && vy > -1.0f && vy < 256.0f &&
          vz > -1.0f && vz < 256.0f))
        return 0.0f;
    const float fx0 = floorf(vx), fy0 = floorf(vy), fz0 = floorf(vz);
    const int x0 = (int)fx0, y0 = (int)fy0, z0 = (int)fz0;
    const float fx = vx - fx0, fy = vy - fy0, fz = vz - fz0;
    float sum = 0.0f;
    #pragma unroll
    for (int dzz = 0; dzz < 2; ++dzz) {
        const float wz = dzz ? fz : 1.0f - fz;
        const int zi = z0 + dzz;
        #pragma unroll
        for (int dyy = 0; dyy < 2; ++dyy) {
            const float wy = dyy ? fy : 1.0f - fy;
            const int yi = y0 + dyy;
            #pragma unroll
            for (int dxx = 0; dxx < 2; ++dxx) {
                const float wx = dxx ? fx : 1.0f - fx;
                const int xi = x0 + dxx;
                if ((unsigned)xi < 256u && (unsigned)yi < 256u && (unsigned)zi < 256u)
                    sum += wz * wy * wx * vol[(zi << 16) | (yi << 8) | xi];
            }
        }
    }
    return sum;
}

struct Spans { int g0, s0, s1, g1; float dx, dy, dz, bx, by, bz; float cb, sb; };

__device__ __forceinline__ Spans ray_setup(const float* __restrict__ angles, int tid) {
    Spans sp;
    const int col = tid % NCOL;
    const int rv  = tid / NCOL;
    const int row = rv % NROW;
    const int view = rv / NROW;

    const float beta = angles[view];
    const float cb = cosf(beta), sb = sinf(beta);
    sp.cb = cb; sp.sb = sb;
    const float u = (col - NCOL * 0.5f + 0.5f) * DET_U;
    const float v = (row - NROW * 0.5f + 0.5f) * DET_V;

    const float sx = ISO * cb, sy = ISO * sb;               // source (z=0)
    const float detx = -(SDD - ISO) * cb - u * sb;
    const float dety = -(SDD - ISO) * sb + u * cb;
    const float detz = v;

    float dx = detx - sx, dy = dety - sy, dz = detz;
    const float inv = 1.0f / sqrtf(dx * dx + dy * dy + dz * dz);
    dx *= inv; dy *= inv; dz *= inv;
    sp.dx = dx; sp.dy = dy; sp.dz = dz;
    sp.bx = sx + 127.5f; sp.by = sy + 127.5f; sp.bz = 127.5f;

    float xl, xh, yl, yh, zl, zh;
    axis_interval(sp.bx, dx, 0.01f, 254.99f, xl, xh);
    axis_interval(sp.by, dy, 0.01f, 254.99f, yl, yh);
    axis_interval(sp.bz, dz, 0.01f, 254.99f, zl, zh);
    const float tin  = fmaxf(xl, fmaxf(yl, zl));
    const float tout = fminf(xh, fminf(yh, zh));

    axis_interval(sp.bx, dx, -1.05f, 256.05f, xl, xh);
    axis_interval(sp.by, dy, -1.05f, 256.05f, yl, yh);
    axis_interval(sp.bz, dz, -1.05f, 256.05f, zl, zh);
    const float glo = fmaxf(xl, fmaxf(yl, zl));
    const float ghi = fminf(xh, fminf(yh, zh));

    const float invdt = 1.0f / DT;
    float g0f = floorf((glo - T0) * invdt - 0.5f);
    float g1f = ceilf((ghi - T0) * invdt - 0.5f) + 1.0f;
    float s0f = ceilf((tin - T0) * invdt - 0.5f + 0.01f);
    float s1f = floorf((tout - T0) * invdt - 0.5f - 0.01f) + 1.0f;
    int g0 = (int)fminf(fmaxf(g0f, 0.0f), 256.0f);
    int g1 = (int)fminf(fmaxf(g1f, 0.0f), 256.0f);
    int s0 = (int)fminf(fmaxf(s0f, 0.0f), 256.0f);
    int s1 = (int)fminf(fmaxf(s1f, 0.0f), 256.0f);
    s0 = max(s0, g0); s1 = min(s1, g1);
    if (s1 < s0) { s0 = g0; s1 = g0; }
    sp.g0 = g0; sp.s0 = s0; sp.s1 = s1; sp.g1 = g1;
    return sp;
}

// ---------- quad pack: Q[z][y][x] = uint2{ h2(v(x,y),v(x,y+1)), h2(v(x+1,y),v(x+1,y+1)) }
__global__ __launch_bounds__(256) void quadpack_kernel(const float* __restrict__ vol,
                                                       uint2* __restrict__ Q) {
    const unsigned i = blockIdx.x * 256u + threadIdx.x;   // 16.7M
    const unsigned x = i & 255u, y = (i >> 8) & 255u;
    const float v00 = vol[i];
    const float v01 = (x < 255u) ? vol[i + 1]   : v00;    // x+1, y
    const float v10 = (y < 255u) ? vol[i + 256] : v00;    // x,   y+1
    const float v11 = (x < 255u && y < 255u) ? vol[i + 257] : v00;
    __half2 A = __floats2half2_rn(v00, v10);   // x0: (y0, y1)
    __half2 B = __floats2half2_rn(v01, v11);   // x1: (y0, y1)
    uint2 q;
    q.x = *reinterpret_cast<unsigned*>(&A);
    q.y = *reinterpret_cast<unsigned*>(&B);
    Q[i] = q;
}

// ---------- main: quad gathers (2 loads/sample) + 2-deep prefetch ------------
__global__ __launch_bounds__(256) void projector3d_quad_kernel(
    const float* __restrict__ vol,      // fp32 original (shell path)
    const uint2* __restrict__ Q,        // fp16 xy-quads
    const float* __restrict__ angles,
    float* __restrict__ out)
{
    // view-chunked XCD swizzle (1536 % 8 == 0, bijective): 2 views per XCD
    const int nwg = (NVIEW * NROW * NCOL) / 256;   // 1536
    const int cpx = nwg / 8;                       // 192
    const int bid = blockIdx.x;
    const int swz = (bid % 8) * cpx + bid / 8;
    const int tid = swz * 256 + threadIdx.x;

    const Spans sp = ray_setup(angles, tid);
    const float dx = sp.dx, dy = sp.dy, dz = sp.dz;
    const float bx = sp.bx, by = sp.by, bz = sp.bz;

    float acc = 0.0f;

    for (int s = sp.g0; s < sp.s0; ++s) {
        const float t = T0 + (s + 0.5f) * DT;
        acc += sample_shell(vol, fmaf(t, dx, bx), fmaf(t, dy, by), fmaf(t, dz, bz));
    }

    int s = sp.s0;
    if (s < sp.s1) {
        float t = T0 + (s + 0.5f) * DT;
        float vx = fmaf(t, dx, bx), vy = fmaf(t, dy, by), vz = fmaf(t, dz, bz);
        float fx0 = floorf(vx), fy0 = floorf(vy), fz0 = floorf(vz);
        float fx = vx - fx0, fy = vy - fy0, fz = vz - fz0;
        const uint2* p = Q + (((int)fz0 << 16) | ((int)fy0 << 8) | (int)fx0);
        uint2 q0 = p[0], q1 = p[65536];

        for (++s; s < sp.s1; ++s) {
            // issue next sample's 2 loads first
            t = T0 + (s + 0.5f) * DT;
            const float nvx = fmaf(t, dx, bx), nvy = fmaf(t, dy, by), nvz = fmaf(t, dz, bz);
            const float nfx0 = floorf(nvx), nfy0 = floorf(nvy), nfz0 = floorf(nvz);
            const uint2* np = Q + (((int)nfz0 << 16) | ((int)nfy0 << 8) | (int)nfx0);
            const uint2 nq0 = np[0], nq1 = np[65536];

            // consume current
            {
                const __half2 A0 = *reinterpret_cast<const __half2*>(&q0.x);
                const __half2 B0 = *reinterpret_cast<const __half2*>(&q0.y);
                const __half2 A1 = *reinterpret_cast<const __half2*>(&q1.x);
                const __half2 B1 = *reinterpret_cast<const __half2*>(&q1.y);
                const float a00 = __low2float(A0), a10 = __high2float(A0);
                const float a01 = __low2float(B0), a11 = __high2float(B0);
                const float b00 = __low2float(A1), b10 = __high2float(A1);
                const float b01 = __low2float(B1), b11 = __high2float(B1);
                const float cy0z0 = fmaf(fx, a01 - a00, a00);
                const float cy1z0 = fmaf(fx, a11 - a10, a10);
                const float cy0z1 = fmaf(fx, b01 - b00, b00);
                const float cy1z1 = fmaf(fx, b11 - b10, b10);
                const float cz0 = fmaf(fy, cy1z0 - cy0z0, cy0z0);
                const float cz1 = fmaf(fy, cy1z1 - cy0z1, cy0z1);
                acc += fmaf(fz, cz1 - cz0, cz0);
            }
            fx = nvx - nfx0; fy = nvy - nfy0; fz = nvz - nfz0;
            q0 = nq0; q1 = nq1;
        }
        // drain last
        {
            const __half2 A0 = *reinterpret_cast<const __half2*>(&q0.x);
            const __half2 B0 = *reinterpret_cast<const __half2*>(&q0.y);
            const __half2 A1 = *reinterpret_cast<const __half2*>(&q1.x);
            const __half2 B1 = *reinterpret_cast<const __half2*>(&q1.y);
            const float a00 = __low2float(A0), a10 = __high2float(A0);
            const float a01 = __low2float(B0), a11 = __high2float(B0);
            const float b00 = __low2float(A1), b10 = __high2float(A1);
            const float b01 = __low2float(B1), b11 = __high2float(B1);
            const float cy0z0 = fmaf(fx, a01 - a00, a00);
            const float cy1z0 = fmaf(fx, a11 - a10, a10);
            const float cy0z1 = fmaf(fx, b01 - b00, b00);
            const float cy1z1 = fmaf(fx, b11 - b10, b10);
            const float cz0 = fmaf(fy, cy1z0 - cy0z0, cy0z0);
            const float cz1 = fmaf(fy, cy1z1 - cy0z1, cy0z1);
            acc += fmaf(fz, cz1 - cz0, cz0);
        }
    }

    for (int s2 = sp.s1; s2 < sp.g1; ++s2) {
        const float t = T0 + (s2 + 0.5f) * DT;
        acc += sample_shell(vol, fmaf(t, dx, bx), fmaf(t, dy, by), fmaf(t, dz, bz));
    }

    out[tid] = acc * DT;
}

// ---------- fallback A: transpose + dual-layout fp32 (round-8) ---------------
__global__ __launch_bounds__(256) void transpose_kernel(const float* __restrict__ vol,
                                                        float* __restrict__ volT) {
    __shared__ float tile[32][33];
    const int z = blockIdx.z;
    const int x0 = blockIdx.x * 32, y0 = blockIdx.y * 32;
    const int tx = threadIdx.x, ty = threadIdx.y;   // 32 x 8
    const float* src = vol + (z << 16);
    float* dst = volT + (z << 16);
    #pragma unroll
    for (int i = 0; i < 32; i += 8)
        tile[ty + i][tx] = src[((y0 + ty + i) << 8) | (x0 + tx)];
    __syncthreads();
    #pragma unroll
    for (int i = 0; i < 32; i += 8)
        dst[((x0 + ty + i) << 8) | (y0 + tx)] = tile[tx][ty + i];
}

__global__ __launch_bounds__(256) void projector3d_dual_kernel(
    const float* __restrict__ vol, const float* __restrict__ volT,
    const float* __restrict__ angles, float* __restrict__ out)
{
    const int tid = blockIdx.x * 256 + threadIdx.x;
    const Spans sp = ray_setup(angles, tid);
    const float dx = sp.dx, dy = sp.dy, dz = sp.dz;
    const float bx = sp.bx, by = sp.by, bz = sp.bz;
    const bool useT = fabsf(sp.cb) > fabsf(sp.sb);
    const float* __restrict__ P = useT ? volT : vol;
    const float da = useT ? dy : dx, db = useT ? dx : dy;
    const float ba = useT ? by : bx, bb = useT ? bx : by;

    float acc = 0.0f;
    for (int s = sp.g0; s < sp.s0; ++s) {
        const float t = T0 + (s + 0.5f) * DT;
        acc += sample_shell(vol, fmaf(t, dx, bx), fmaf(t, dy, by), fmaf(t, dz, bz));
    }
    for (int s = sp.s0; s < sp.s1; ++s) {
        const float t = T0 + (s + 0.5f) * DT;
        const float va = fmaf(t, da, ba), vb = fmaf(t, db, bb), vc = fmaf(t, dz, bz);
        const float fa0 = floorf(va), fb0 = floorf(vb), fc0 = floorf(vc);
        const float fa = va - fa0, fb = vb - fb0, fc = vc - fc0;
        const float* p = P + (((int)fc0 << 16) | ((int)fb0 << 8) | (int)fa0);
        const float v000 = p[0],     v001 = p[1];
        const float v010 = p[256],   v011 = p[257];
        const float v100 = p[65536], v101 = p[65537];
        const float v110 = p[65792], v111 = p[65793];
        const float c00 = fmaf(fa, v001 - v000, v000);
        const float c01 = fmaf(fa, v011 - v010, v010);
        const float c10 = fmaf(fa, v101 - v100, v100);
        const float c11 = fmaf(fa, v111 - v110, v110);
        const float c0 = fmaf(fb, c01 - c00, c00);
        const float c1 = fmaf(fb, c11 - c10, c10);
        acc += fmaf(fc, c1 - c0, c0);
    }
    for (int s = sp.s1; s < sp.g1; ++s) {
        const float t = T0 + (s + 0.5f) * DT;
        acc += sample_shell(vol, fmaf(t, dx, bx), fmaf(t, dy, by), fmaf(t, dz, bz));
    }
    out[tid] = acc * DT;
}

// ---------- fallback B: plain fp32 -------------------------------------------
__global__ __launch_bounds__(256) void projector3d_f32_kernel(
    const float* __restrict__ vol, const float* __restrict__ angles,
    float* __restrict__ out)
{
    const int tid = blockIdx.x * 256 + threadIdx.x;
    const Spans sp = ray_setup(angles, tid);
    const float dx = sp.dx, dy = sp.dy, dz = sp.dz;
    const float bx = sp.bx, by = sp.by, bz = sp.bz;
    float acc = 0.0f;
    for (int s = sp.g0; s < sp.s0; ++s) {
        const float t = T0 + (s + 0.5f) * DT;
        acc += sample_shell(vol, fmaf(t, dx, bx), fmaf(t, dy, by), fmaf(t, dz, bz));
    }
    #pragma unroll 4
    for (int s = sp.s0; s < sp.s1; ++s) {
        const float t = T0 + (s + 0.5f) * DT;
        const float vx = fmaf(t, dx, bx), vy = fmaf(t, dy, by), vz = fmaf(t, dz, bz);
        const float fx0 = floorf(vx), fy0 = floorf(vy), fz0 = floorf(vz);
        const int x0 = (int)fx0, y0 = (int)fy0, z0 = (int)fz0;
        const float fx = vx - fx0, fy = vy - fy0, fz = vz - fz0;
        const float* p = vol + ((z0 << 16) | (y0 << 8) | x0);
        const float v000 = p[0],     v001 = p[1];
        const float v010 = p[256],   v011 = p[257];
        const float v100 = p[65536], v101 = p[65537];
        const float v110 = p[65792], v111 = p[65793];
        const float c00 = fmaf(fx, v001 - v000, v000);
        const float c01 = fmaf(fx, v011 - v010, v010);
        const float c10 = fmaf(fx, v101 - v100, v100);
        const float c11 = fmaf(fx, v111 - v110, v110);
        const float c0 = fmaf(fy, c01 - c00, c00);
        const float c1 = fmaf(fy, c11 - c10, c10);
        acc += fmaf(fz, c1 - c0, c0);
    }
    for (int s = sp.s1; s < sp.g1; ++s) {
        const float t = T0 + (s + 0.5f) * DT;
        acc += sample_shell(vol, fmaf(t, dx, bx), fmaf(t, dy, by), fmaf(t, dz, bz));
    }
    out[tid] = acc * DT;
}

extern "C" void kernel_launch(void* const* d_in, const int* in_sizes, int n_in,
                              void* d_out, int out_size, void* d_ws, size_t ws_size,
                              hipStream_t stream) {
    const float* vol    = (const float*)d_in[0];
    const float* angles = (const float*)d_in[1];
    float* out = (float*)d_out;

    const int grid = (NVIEW * NROW * NCOL) / 256;       // 1536
    if (ws_size >= VOL_N * sizeof(uint2)) {             // 134 MB: fp16 xy-quad
        uint2* Q = (uint2*)d_ws;
        quadpack_kernel<<<(int)(VOL_N / 256), 256, 0, stream>>>(vol, Q);
        projector3d_quad_kernel<<<grid, 256, 0, stream>>>(vol, Q, angles, out);
    } else if (ws_size >= VOL_N * sizeof(float)) {      // 67 MB: dual-layout fp32
        float* volT = (float*)d_ws;
        dim3 tgrid(8, 8, 256), tblk(32, 8);
        transpose_kernel<<<tgrid, tblk, 0, stream>>>(vol, volT);
        projector3d_dual_kernel<<<grid, 256, 0, stream>>>(vol, volT, angles, out);
    } else {
        projector3d_f32_kernel<<<grid, 256, 0, stream>>>(vol, angles, out);
    }
}

// Round 12
// 264.733 us; speedup vs baseline: 1.5594x; 1.5594x over previous
//
#include <hip/hip_runtime.h>
#include <hip/hip_fp16.h>
#include <math.h>

namespace {
constexpr int NCOL = 384, NROW = 64, NVIEW = 16, NSAMP = 256;
constexpr float DET_U = 1.2f, DET_V = 1.2f;
constexpr float ISO = 500.0f, SDD = 1000.0f;
constexpr double SQRT3 = 1.7320508075688772;
constexpr float DT = (float)SQRT3;                          // RAY_LEN / NSAMP
constexpr float T0 = (float)(500.0 - SQRT3 * 256.0 * 0.5); // ISO - RAY_LEN/2
constexpr size_t VOL_N = 256u * 256u * 256u;               // 16.7M voxels
}

// t-interval where p0 + t*d lies in [LO, HI]; empty -> [1e30, -1e30]
__device__ __forceinline__ void axis_interval(float p0, float d, float LO, float HI,
                                              float& tlo, float& thi) {
    if (fabsf(d) < 1e-7f) {
        if (p0 < LO || p0 > HI) { tlo = 1e30f; thi = -1e30f; }
        else                    { tlo = -1e30f; thi = 1e30f; }
    } else {
        const float r = 1.0f / d;
        const float t1 = (LO - p0) * r, t2 = (HI - p0) * r;
        tlo = fminf(t1, t2); thi = fmaxf(t1, t2);
    }
}

// general (shell) sample on the ORIGINAL fp32 volume: per-corner check
__device__ __forceinline__ float sample_shell(const float* __restrict__ vol,
                                              float vx, float vy, float vz) {
    if (!(vx > -1.0f && vx < 256.0f && vy > -1.0f && vy < 256.0f &&
          vz > -1.0f && vz < 256.0f))
        return 0.0f;
    const float fx0 = floorf(vx), fy0 = floorf(vy), fz0 = floorf(vz);
    const int x0 = (int)fx0, y0 = (int)fy0, z0 = (int)fz0;
    const float fx = vx - fx0, fy = vy - fy0, fz = vz - fz0;
    float sum = 0.0f;
    #pragma unroll
    for (int dzz = 0; dzz < 2; ++dzz) {
        const float wz = dzz ? fz : 1.0f - fz;
        const int zi = z0 + dzz;
        #pragma unroll
        for (int dyy = 0; dyy < 2; ++dyy) {
            const float wy = dyy ? fy : 1.0f - fy;
            const int yi = y0 + dyy;
            #pragma unroll
            for (int dxx = 0; dxx < 2; ++dxx) {
                const float wx = dxx ? fx : 1.0f - fx;
                const int xi = x0 + dxx;
                if ((unsigned)xi < 256u && (unsigned)yi < 256u && (unsigned)zi < 256u)
                    sum += wz * wy * wx * vol[(zi << 16) | (yi << 8) | xi];
            }
        }
    }
    return sum;
}

struct Spans { int g0, s0, s1, g1; float dx, dy, dz, bx, by, bz; float cb, sb; };

__device__ __forceinline__ Spans ray_setup(const float* __restrict__ angles, int tid) {
    Spans sp;
    const int col = tid % NCOL;
    const int rv  = tid / NCOL;
    const int row = rv % NROW;
    const int view = rv / NROW;

    const float beta = angles[view];
    const float cb = cosf(beta), sb = sinf(beta);
    sp.cb = cb; sp.sb = sb;
    const float u = (col - NCOL * 0.5f + 0.5f) * DET_U;
    const float v = (row - NROW * 0.5f + 0.5f) * DET_V;

    const float sx = ISO * cb, sy = ISO * sb;               // source (z=0)
    const float detx = -(SDD - ISO) * cb - u * sb;
    const float dety = -(SDD - ISO) * sb + u * cb;
    const float detz = v;

    float dx = detx - sx, dy = dety - sy, dz = detz;
    const float inv = 1.0f / sqrtf(dx * dx + dy * dy + dz * dz);
    dx *= inv; dy *= inv; dz *= inv;
    sp.dx = dx; sp.dy = dy; sp.dz = dz;
    sp.bx = sx + 127.5f; sp.by = sy + 127.5f; sp.bz = 127.5f;

    float xl, xh, yl, yh, zl, zh;
    axis_interval(sp.bx, dx, 0.01f, 254.99f, xl, xh);
    axis_interval(sp.by, dy, 0.01f, 254.99f, yl, yh);
    axis_interval(sp.bz, dz, 0.01f, 254.99f, zl, zh);
    const float tin  = fmaxf(xl, fmaxf(yl, zl));
    const float tout = fminf(xh, fminf(yh, zh));

    axis_interval(sp.bx, dx, -1.05f, 256.05f, xl, xh);
    axis_interval(sp.by, dy, -1.05f, 256.05f, yl, yh);
    axis_interval(sp.bz, dz, -1.05f, 256.05f, zl, zh);
    const float glo = fmaxf(xl, fmaxf(yl, zl));
    const float ghi = fminf(xh, fminf(yh, zh));

    const float invdt = 1.0f / DT;
    float g0f = floorf((glo - T0) * invdt - 0.5f);
    float g1f = ceilf((ghi - T0) * invdt - 0.5f) + 1.0f;
    float s0f = ceilf((tin - T0) * invdt - 0.5f + 0.01f);
    float s1f = floorf((tout - T0) * invdt - 0.5f - 0.01f) + 1.0f;
    int g0 = (int)fminf(fmaxf(g0f, 0.0f), 256.0f);
    int g1 = (int)fminf(fmaxf(g1f, 0.0f), 256.0f);
    int s0 = (int)fminf(fmaxf(s0f, 0.0f), 256.0f);
    int s1 = (int)fminf(fmaxf(s1f, 0.0f), 256.0f);
    s0 = max(s0, g0); s1 = min(s1, g1);
    if (s1 < s0) { s0 = g0; s1 = g0; }
    sp.g0 = g0; sp.s0 = s0; sp.s1 = s1; sp.g1 = g1;
    return sp;
}

// ---------- pack P[z][y][x] = half2( v[z][y][x], v[z+1][y][x] ) --------------
__global__ __launch_bounds__(256) void packP_kernel(const float* __restrict__ vol,
                                                    __half2* __restrict__ P) {
    const unsigned i = blockIdx.x * 256u + threadIdx.x;   // 16.7M
    const unsigned z = i >> 16;
    const float a = vol[i];
    const float b = (z < 255u) ? vol[i + 65536] : a;
    P[i] = __floats2half2_rn(a, b);
}

// ---------- pack PT[z][x][y] = half2( v[z][y][x], v[z+1][y][x] ) -------------
__global__ __launch_bounds__(256) void packPT_kernel(const float* __restrict__ vol,
                                                     __half2* __restrict__ PT) {
    __shared__ __half2 tile[32][33];
    const int z = blockIdx.z;
    const int z1 = (z < 255) ? z + 1 : 255;
    const int x0 = blockIdx.x * 32, y0 = blockIdx.y * 32;
    const int tx = threadIdx.x, ty = threadIdx.y;   // 32 x 8
    const float* s0 = vol + (z  << 16);
    const float* s1 = vol + (z1 << 16);
    #pragma unroll
    for (int i = 0; i < 32; i += 8) {
        const int idx = ((y0 + ty + i) << 8) | (x0 + tx);
        tile[ty + i][tx] = __floats2half2_rn(s0[idx], s1[idx]);
    }
    __syncthreads();
    __half2* d = PT + (z << 16);
    #pragma unroll
    for (int i = 0; i < 32; i += 8)
        d[((x0 + ty + i) << 8) | (y0 + tx)] = tile[tx][ty + i];
}

// lerp in z from a packed pair
__device__ __forceinline__ float zlerp(__half2 q, float fc) {
    const float lo = __low2float(q), hi = __high2float(q);
    return fmaf(fc, hi - lo, lo);
}

// ---------- main: z-pair dual-layout, 4 loads/sample, 2-deep prefetch --------
__global__ __launch_bounds__(256) void projector3d_zp_kernel(
    const float* __restrict__ vol,       // fp32 original (shell path)
    const __half2* __restrict__ P,       // z-pairs, x-inner
    const __half2* __restrict__ PT,      // z-pairs, y-inner
    const float* __restrict__ angles,
    float* __restrict__ out)
{
    const int tid = blockIdx.x * 256 + threadIdx.x;   // no swizzle (proven better)

    const Spans sp = ray_setup(angles, tid);
    const float dx = sp.dx, dy = sp.dy, dz = sp.dz;
    const float bx = sp.bx, by = sp.by, bz = sp.bz;

    // lanes spread along detector-u = (-sb, cb, 0): pick layout whose inner
    // axis matches (|cb|>|sb| -> spread in y -> y-inner PT, swap roles of x/y)
    const bool useT = fabsf(sp.cb) > fabsf(sp.sb);
    const __half2* __restrict__ Pm = useT ? PT : P;
    const float da = useT ? dy : dx, db = useT ? dx : dy;
    const float ba = useT ? by : bx, bb = useT ? bx : by;

    float acc = 0.0f;

    for (int s = sp.g0; s < sp.s0; ++s) {
        const float t = T0 + (s + 0.5f) * DT;
        acc += sample_shell(vol, fmaf(t, dx, bx), fmaf(t, dy, by), fmaf(t, dz, bz));
    }

    int s = sp.s0;
    if (s < sp.s1) {
        // prologue: load sample s
        float t = T0 + (s + 0.5f) * DT;
        float va = fmaf(t, da, ba), vb = fmaf(t, db, bb), vc = fmaf(t, dz, bz);
        float fa0 = floorf(va), fb0 = floorf(vb), fc0 = floorf(vc);
        float fa = va - fa0, fb = vb - fb0, fc = vc - fc0;
        const __half2* p = Pm + (((int)fc0 << 16) | ((int)fb0 << 8) | (int)fa0);
        __half2 q00 = p[0], q01 = p[1], q10 = p[256], q11 = p[257];

        for (++s; s < sp.s1; ++s) {
            // issue next sample's 4 loads first
            t = T0 + (s + 0.5f) * DT;
            const float nva = fmaf(t, da, ba), nvb = fmaf(t, db, bb), nvc = fmaf(t, dz, bz);
            const float nfa0 = floorf(nva), nfb0 = floorf(nvb), nfc0 = floorf(nvc);
            const __half2* np = Pm + (((int)nfc0 << 16) | ((int)nfb0 << 8) | (int)nfa0);
            const __half2 nq00 = np[0], nq01 = np[1], nq10 = np[256], nq11 = np[257];

            // consume current: z-lerp then bilinear (a inner, b mid)
            const float v00 = zlerp(q00, fc), v01 = zlerp(q01, fc);
            const float v10 = zlerp(q10, fc), v11 = zlerp(q11, fc);
            const float ca0 = fmaf(fa, v01 - v00, v00);
            const float ca1 = fmaf(fa, v11 - v10, v10);
            acc += fmaf(fb, ca1 - ca0, ca0);

            fa = nva - nfa0; fb = nvb - nfb0; fc = nvc - nfc0;
            q00 = nq00; q01 = nq01; q10 = nq10; q11 = nq11;
        }
        // drain last
        const float v00 = zlerp(q00, fc), v01 = zlerp(q01, fc);
        const float v10 = zlerp(q10, fc), v11 = zlerp(q11, fc);
        const float ca0 = fmaf(fa, v01 - v00, v00);
        const float ca1 = fmaf(fa, v11 - v10, v10);
        acc += fmaf(fb, ca1 - ca0, ca0);
    }

    for (int s2 = sp.s1; s2 < sp.g1; ++s2) {
        const float t = T0 + (s2 + 0.5f) * DT;
        acc += sample_shell(vol, fmaf(t, dx, bx), fmaf(t, dy, by), fmaf(t, dz, bz));
    }

    out[tid] = acc * DT;
}

// ---------- fallback A: transpose + dual-layout fp32 (round-8, 262us) --------
__global__ __launch_bounds__(256) void transpose_kernel(const float* __restrict__ vol,
                                                        float* __restrict__ volT) {
    __shared__ float tile[32][33];
    const int z = blockIdx.z;
    const int x0 = blockIdx.x * 32, y0 = blockIdx.y * 32;
    const int tx = threadIdx.x, ty = threadIdx.y;   // 32 x 8
    const float* src = vol + (z << 16);
    float* dst = volT + (z << 16);
    #pragma unroll
    for (int i = 0; i < 32; i += 8)
        tile[ty + i][tx] = src[((y0 + ty + i) << 8) | (x0 + tx)];
    __syncthreads();
    #pragma unroll
    for (int i = 0; i < 32; i += 8)
        dst[((x0 + ty + i) << 8) | (y0 + tx)] = tile[tx][ty + i];
}

__global__ __launch_bounds__(256) void projector3d_dual_kernel(
    const float* __restrict__ vol, const float* __restrict__ volT,
    const float* __restrict__ angles, float* __restrict__ out)
{
    const int tid = blockIdx.x * 256 + threadIdx.x;
    const Spans sp = ray_setup(angles, tid);
    const float dx = sp.dx, dy = sp.dy, dz = sp.dz;
    const float bx = sp.bx, by = sp.by, bz = sp.bz;
    const bool useT = fabsf(sp.cb) > fabsf(sp.sb);
    const float* __restrict__ Pm = useT ? volT : vol;
    const float da = useT ? dy : dx, db = useT ? dx : dy;
    const float ba = useT ? by : bx, bb = useT ? bx : by;

    float acc = 0.0f;
    for (int s = sp.g0; s < sp.s0; ++s) {
        const float t = T0 + (s + 0.5f) * DT;
        acc += sample_shell(vol, fmaf(t, dx, bx), fmaf(t, dy, by), fmaf(t, dz, bz));
    }
    for (int s = sp.s0; s < sp.s1; ++s) {
        const float t = T0 + (s + 0.5f) * DT;
        const float va = fmaf(t, da, ba), vb = fmaf(t, db, bb), vc = fmaf(t, dz, bz);
        const float fa0 = floorf(va), fb0 = floorf(vb), fc0 = floorf(vc);
        const float fa = va - fa0, fb = vb - fb0, fc = vc - fc0;
        const float* p = Pm + (((int)fc0 << 16) | ((int)fb0 << 8) | (int)fa0);
        const float v000 = p[0],     v001 = p[1];
        const float v010 = p[256],   v011 = p[257];
        const float v100 = p[65536], v101 = p[65537];
        const float v110 = p[65792], v111 = p[65793];
        const float c00 = fmaf(fa, v001 - v000, v000);
        const float c01 = fmaf(fa, v011 - v010, v010);
        const float c10 = fmaf(fa, v101 - v100, v100);
        const float c11 = fmaf(fa, v111 - v110, v110);
        const float c0 = fmaf(fb, c01 - c00, c00);
        const float c1 = fmaf(fb, c11 - c10, c10);
        acc += fmaf(fc, c1 - c0, c0);
    }
    for (int s = sp.s1; s < sp.g1; ++s) {
        const float t = T0 + (s + 0.5f) * DT;
        acc += sample_shell(vol, fmaf(t, dx, bx), fmaf(t, dy, by), fmaf(t, dz, bz));
    }
    out[tid] = acc * DT;
}

// ---------- fallback B: plain fp32 -------------------------------------------
__global__ __launch_bounds__(256) void projector3d_f32_kernel(
    const float* __restrict__ vol, const float* __restrict__ angles,
    float* __restrict__ out)
{
    const int tid = blockIdx.x * 256 + threadIdx.x;
    const Spans sp = ray_setup(angles, tid);
    const float dx = sp.dx, dy = sp.dy, dz = sp.dz;
    const float bx = sp.bx, by = sp.by, bz = sp.bz;
    float acc = 0.0f;
    for (int s = sp.g0; s < sp.s0; ++s) {
        const float t = T0 + (s + 0.5f) * DT;
        acc += sample_shell(vol, fmaf(t, dx, bx), fmaf(t, dy, by), fmaf(t, dz, bz));
    }
    #pragma unroll 4
    for (int s = sp.s0; s < sp.s1; ++s) {
        const float t = T0 + (s + 0.5f) * DT;
        const float vx = fmaf(t, dx, bx), vy = fmaf(t, dy, by), vz = fmaf(t, dz, bz);
        const float fx0 = floorf(vx), fy0 = floorf(vy), fz0 = floorf(vz);
        const int x0 = (int)fx0, y0 = (int)fy0, z0 = (int)fz0;
        const float fx = vx - fx0, fy = vy - fy0, fz = vz - fz0;
        const float* p = vol + ((z0 << 16) | (y0 << 8) | x0);
        const float v000 = p[0],     v001 = p[1];
        const float v010 = p[256],   v011 = p[257];
        const float v100 = p[65536], v101 = p[65537];
        const float v110 = p[65792], v111 = p[65793];
        const float c00 = fmaf(fx, v001 - v000, v000);
        const float c01 = fmaf(fx, v011 - v010, v010);
        const float c10 = fmaf(fx, v101 - v100, v100);
        const float c11 = fmaf(fx, v111 - v110, v110);
        const float c0 = fmaf(fy, c01 - c00, c00);
        const float c1 = fmaf(fy, c11 - c10, c10);
        acc += fmaf(fz, c1 - c0, c0);
    }
    for (int s = sp.s1; s < sp.g1; ++s) {
        const float t = T0 + (s + 0.5f) * DT;
        acc += sample_shell(vol, fmaf(t, dx, bx), fmaf(t, dy, by), fmaf(t, dz, bz));
    }
    out[tid] = acc * DT;
}

extern "C" void kernel_launch(void* const* d_in, const int* in_sizes, int n_in,
                              void* d_out, int out_size, void* d_ws, size_t ws_size,
                              hipStream_t stream) {
    const float* vol    = (const float*)d_in[0];
    const float* angles = (const float*)d_in[1];
    float* out = (float*)d_out;

    const int grid = (NVIEW * NROW * NCOL) / 256;       // 1536
    if (ws_size >= 2u * VOL_N * sizeof(__half2) / 1) {  // 134 MB: z-pair dual
        __half2* P  = (__half2*)d_ws;
        __half2* PT = P + VOL_N;
        packP_kernel<<<(int)(VOL_N / 256), 256, 0, stream>>>(vol, P);
        dim3 tgrid(8, 8, 256), tblk(32, 8);
        packPT_kernel<<<tgrid, tblk, 0, stream>>>(vol, PT);
        projector3d_zp_kernel<<<grid, 256, 0, stream>>>(vol, P, PT, angles, out);
    } else if (ws_size >= VOL_N * sizeof(float)) {      // 67 MB: dual-layout fp32
        float* volT = (float*)d_ws;
        dim3 tgrid(8, 8, 256), tblk(32, 8);
        transpose_kernel<<<tgrid, tblk, 0, stream>>>(vol, volT);
        projector3d_dual_kernel<<<grid, 256, 0, stream>>>(vol, volT, angles, out);
    } else {
        projector3d_f32_kernel<<<grid, 256, 0, stream>>>(vol, angles, out);
    }
}

// Round 13
// 255.029 us; speedup vs baseline: 1.6187x; 1.0381x over previous
//
#include <hip/hip_runtime.h>
#include <hip/hip_fp16.h>
#include <math.h>

namespace {
constexpr int NCOL = 384, NROW = 64, NVIEW = 16, NSAMP = 256;
constexpr float DET_U = 1.2f, DET_V = 1.2f;
constexpr float ISO = 500.0f, SDD = 1000.0f;
constexpr double SQRT3 = 1.7320508075688772;
constexpr float DT = (float)SQRT3;                          // RAY_LEN / NSAMP
constexpr float T0 = (float)(500.0 - SQRT3 * 256.0 * 0.5); // ISO - RAY_LEN/2
constexpr size_t VOL_N = 256u * 256u * 256u;               // 16.7M voxels
}

// t-interval where p0 + t*d lies in [LO, HI]; empty -> [1e30, -1e30]
__device__ __forceinline__ void axis_interval(float p0, float d, float LO, float HI,
                                              float& tlo, float& thi) {
    if (fabsf(d) < 1e-7f) {
        if (p0 < LO || p0 > HI) { tlo = 1e30f; thi = -1e30f; }
        else                    { tlo = -1e30f; thi = 1e30f; }
    } else {
        const float r = 1.0f / d;
        const float t1 = (LO - p0) * r, t2 = (HI - p0) * r;
        tlo = fminf(t1, t2); thi = fmaxf(t1, t2);
    }
}

// general (shell) sample on the ORIGINAL fp32 volume: per-corner check
__device__ __forceinline__ float sample_shell(const float* __restrict__ vol,
                                              float vx, float vy, float vz) {
    if (!(vx > -1.0f && vx < 256.0f && vy > -1.0f && vy < 256.0f &&
          vz > -1.0f && vz < 256.0f))
        return 0.0f;
    const float fx0 = floorf(vx), fy0 = floorf(vy), fz0 = floorf(vz);
    const int x0 = (int)fx0, y0 = (int)fy0, z0 = (int)fz0;
    const float fx = vx - fx0, fy = vy - fy0, fz = vz - fz0;
    float sum = 0.0f;
    #pragma unroll
    for (int dzz = 0; dzz < 2; ++dzz) {
        const float wz = dzz ? fz : 1.0f - fz;
        const int zi = z0 + dzz;
        #pragma unroll
        for (int dyy = 0; dyy < 2; ++dyy) {
            const float wy = dyy ? fy : 1.0f - fy;
            const int yi = y0 + dyy;
            #pragma unroll
            for (int dxx = 0; dxx < 2; ++dxx) {
                const float wx = dxx ? fx : 1.0f - fx;
                const int xi = x0 + dxx;
                if ((unsigned)xi < 256u && (unsigned)yi < 256u && (unsigned)zi < 256u)
                    sum += wz * wy * wx * vol[(zi << 16) | (yi << 8) | xi];
            }
        }
    }
    return sum;
}

struct Spans { int g0, s0, s1, g1; float dx, dy, dz, bx, by, bz; float cb, sb; };

__device__ __forceinline__ Spans ray_setup(const float* __restrict__ angles, int tid) {
    Spans sp;
    const int col = tid % NCOL;
    const int rv  = tid / NCOL;
    const int row = rv % NROW;
    const int view = rv / NROW;

    const float beta = angles[view];
    const float cb = cosf(beta), sb = sinf(beta);
    sp.cb = cb; sp.sb = sb;
    const float u = (col - NCOL * 0.5f + 0.5f) * DET_U;
    const float v = (row - NROW * 0.5f + 0.5f) * DET_V;

    const float sx = ISO * cb, sy = ISO * sb;               // source (z=0)
    const float detx = -(SDD - ISO) * cb - u * sb;
    const float dety = -(SDD - ISO) * sb + u * cb;
    const float detz = v;

    float dx = detx - sx, dy = dety - sy, dz = detz;
    const float inv = 1.0f / sqrtf(dx * dx + dy * dy + dz * dz);
    dx *= inv; dy *= inv; dz *= inv;
    sp.dx = dx; sp.dy = dy; sp.dz = dz;
    sp.bx = sx + 127.5f; sp.by = sy + 127.5f; sp.bz = 127.5f;

    float xl, xh, yl, yh, zl, zh;
    axis_interval(sp.bx, dx, 0.01f, 254.99f, xl, xh);
    axis_interval(sp.by, dy, 0.01f, 254.99f, yl, yh);
    axis_interval(sp.bz, dz, 0.01f, 254.99f, zl, zh);
    const float tin  = fmaxf(xl, fmaxf(yl, zl));
    const float tout = fminf(xh, fminf(yh, zh));

    axis_interval(sp.bx, dx, -1.05f, 256.05f, xl, xh);
    axis_interval(sp.by, dy, -1.05f, 256.05f, yl, yh);
    axis_interval(sp.bz, dz, -1.05f, 256.05f, zl, zh);
    const float glo = fmaxf(xl, fmaxf(yl, zl));
    const float ghi = fminf(xh, fminf(yh, zh));

    const float invdt = 1.0f / DT;
    float g0f = floorf((glo - T0) * invdt - 0.5f);
    float g1f = ceilf((ghi - T0) * invdt - 0.5f) + 1.0f;
    float s0f = ceilf((tin - T0) * invdt - 0.5f + 0.01f);
    float s1f = floorf((tout - T0) * invdt - 0.5f - 0.01f) + 1.0f;
    int g0 = (int)fminf(fmaxf(g0f, 0.0f), 256.0f);
    int g1 = (int)fminf(fmaxf(g1f, 0.0f), 256.0f);
    int s0 = (int)fminf(fmaxf(s0f, 0.0f), 256.0f);
    int s1 = (int)fminf(fmaxf(s1f, 0.0f), 256.0f);
    s0 = max(s0, g0); s1 = min(s1, g1);
    if (s1 < s0) { s0 = g0; s1 = g0; }
    sp.g0 = g0; sp.s0 = s0; sp.s1 = s1; sp.g1 = g1;
    return sp;
}

// ---------- fused pack: P[z][y][x] and PT[z][x][y], both = half2(v[z], v[z+1])
__global__ __launch_bounds__(256) void packBoth_kernel(const float* __restrict__ vol,
                                                       __half2* __restrict__ P,
                                                       __half2* __restrict__ PT) {
    __shared__ __half2 tile[32][33];
    const int z = blockIdx.z;
    const int z1 = (z < 255) ? z + 1 : 255;
    const int x0 = blockIdx.x * 32, y0 = blockIdx.y * 32;
    const int tx = threadIdx.x, ty = threadIdx.y;   // 32 x 8
    const float* s0 = vol + (z  << 16);
    const float* s1 = vol + (z1 << 16);
    __half2* Pp = P + (z << 16);
    #pragma unroll
    for (int i = 0; i < 32; i += 8) {
        const int idx = ((y0 + ty + i) << 8) | (x0 + tx);
        const __half2 h = __floats2half2_rn(s0[idx], s1[idx]);
        Pp[idx] = h;                 // x-inner write, coalesced
        tile[ty + i][tx] = h;        // tile[y][x]
    }
    __syncthreads();
    __half2* Tp = PT + (z << 16);
    #pragma unroll
    for (int i = 0; i < 32; i += 8)
        Tp[((x0 + ty + i) << 8) | (y0 + tx)] = tile[tx][ty + i];  // y-inner, coalesced
}

// lerp in z from a packed pair
__device__ __forceinline__ float zlerp(__half2 q, float fc) {
    const float lo = __low2float(q), hi = __high2float(q);
    return fmaf(fc, hi - lo, lo);
}

// per-sample pipeline state (named members -> stays in registers)
struct Smp { float fa, fb, fc; __half2 q00, q01, q10, q11; };

// ---------- main: z-pair dual-layout, 4 loads/sample, 3-deep pipeline --------
__global__ __launch_bounds__(256) void projector3d_zp_kernel(
    const float* __restrict__ vol,       // fp32 original (shell path)
    const __half2* __restrict__ P,       // z-pairs, x-inner
    const __half2* __restrict__ PT,      // z-pairs, y-inner
    const float* __restrict__ angles,
    float* __restrict__ out)
{
    const int tid = blockIdx.x * 256 + threadIdx.x;   // no swizzle (proven better)

    const Spans sp = ray_setup(angles, tid);
    const float dx = sp.dx, dy = sp.dy, dz = sp.dz;
    const float bx = sp.bx, by = sp.by, bz = sp.bz;

    // lanes spread along detector-u = (-sb, cb, 0): pick layout whose inner
    // axis matches (|cb|>|sb| -> spread in y -> y-inner PT, swap roles of x/y)
    const bool useT = fabsf(sp.cb) > fabsf(sp.sb);
    const __half2* __restrict__ Pm = useT ? PT : P;
    const float da = useT ? dy : dx, db = useT ? dx : dy;
    const float ba = useT ? by : bx, bb = useT ? bx : by;

    float acc = 0.0f;

    for (int s = sp.g0; s < sp.s0; ++s) {
        const float t = T0 + (s + 0.5f) * DT;
        acc += sample_shell(vol, fmaf(t, dx, bx), fmaf(t, dy, by), fmaf(t, dz, bz));
    }

    auto LOADS = [&](Smp& S, int si) {
        const float t = T0 + (si + 0.5f) * DT;
        const float va = fmaf(t, da, ba), vb = fmaf(t, db, bb), vc = fmaf(t, dz, bz);
        const float a0 = floorf(va), b0 = floorf(vb), c0 = floorf(vc);
        S.fa = va - a0; S.fb = vb - b0; S.fc = vc - c0;
        const __half2* p = Pm + (((int)c0 << 16) | ((int)b0 << 8) | (int)a0);
        S.q00 = p[0]; S.q01 = p[1]; S.q10 = p[256]; S.q11 = p[257];
    };
    auto CONS = [&](const Smp& S) -> float {
        const float v00 = zlerp(S.q00, S.fc), v01 = zlerp(S.q01, S.fc);
        const float v10 = zlerp(S.q10, S.fc), v11 = zlerp(S.q11, S.fc);
        const float c0 = fmaf(S.fa, v01 - v00, v00);
        const float c1 = fmaf(S.fa, v11 - v10, v10);
        return fmaf(S.fb, c1 - c0, c0);
    };

    // 2-sample-in-flight software pipeline (8 loads outstanding)
    {
        int s = sp.s0;
        const int s1 = sp.s1;
        if (s < s1) {
            Smp A, B;
            LOADS(A, s);
            if (s + 1 < s1) {
                LOADS(B, s + 1);
                s += 2;
                for (; s + 1 < s1; s += 2) {
                    acc += CONS(A); LOADS(A, s);
                    acc += CONS(B); LOADS(B, s + 1);
                }
                if (s < s1) {   // one leftover sample
                    acc += CONS(A); LOADS(A, s);
                    acc += CONS(B);
                    acc += CONS(A);
                } else {
                    acc += CONS(A);
                    acc += CONS(B);
                }
            } else {
                acc += CONS(A);
            }
        }
    }

    for (int s2 = sp.s1; s2 < sp.g1; ++s2) {
        const float t = T0 + (s2 + 0.5f) * DT;
        acc += sample_shell(vol, fmaf(t, dx, bx), fmaf(t, dy, by), fmaf(t, dz, bz));
    }

    out[tid] = acc * DT;
}

// ---------- fallback A: transpose + dual-layout fp32 (round-8, 262us) --------
__global__ __launch_bounds__(256) void transpose_kernel(const float* __restrict__ vol,
                                                        float* __restrict__ volT) {
    __shared__ float tile[32][33];
    const int z = blockIdx.z;
    const int x0 = blockIdx.x * 32, y0 = blockIdx.y * 32;
    const int tx = threadIdx.x, ty = threadIdx.y;   // 32 x 8
    const float* src = vol + (z << 16);
    float* dst = volT + (z << 16);
    #pragma unroll
    for (int i = 0; i < 32; i += 8)
        tile[ty + i][tx] = src[((y0 + ty + i) << 8) | (x0 + tx)];
    __syncthreads();
    #pragma unroll
    for (int i = 0; i < 32; i += 8)
        dst[((x0 + ty + i) << 8) | (y0 + tx)] = tile[tx][ty + i];
}

__global__ __launch_bounds__(256) void projector3d_dual_kernel(
    const float* __restrict__ vol, const float* __restrict__ volT,
    const float* __restrict__ angles, float* __restrict__ out)
{
    const int tid = blockIdx.x * 256 + threadIdx.x;
    const Spans sp = ray_setup(angles, tid);
    const float dx = sp.dx, dy = sp.dy, dz = sp.dz;
    const float bx = sp.bx, by = sp.by, bz = sp.bz;
    const bool useT = fabsf(sp.cb) > fabsf(sp.sb);
    const float* __restrict__ Pm = useT ? volT : vol;
    const float da = useT ? dy : dx, db = useT ? dx : dy;
    const float ba = useT ? by : bx, bb = useT ? bx : by;

    float acc = 0.0f;
    for (int s = sp.g0; s < sp.s0; ++s) {
        const float t = T0 + (s + 0.5f) * DT;
        acc += sample_shell(vol, fmaf(t, dx, bx), fmaf(t, dy, by), fmaf(t, dz, bz));
    }
    for (int s = sp.s0; s < sp.s1; ++s) {
        const float t = T0 + (s + 0.5f) * DT;
        const float va = fmaf(t, da, ba), vb = fmaf(t, db, bb), vc = fmaf(t, dz, bz);
        const float fa0 = floorf(va), fb0 = floorf(vb), fc0 = floorf(vc);
        const float fa = va - fa0, fb = vb - fb0, fc = vc - fc0;
        const float* p = Pm + (((int)fc0 << 16) | ((int)fb0 << 8) | (int)fa0);
        const float v000 = p[0],     v001 = p[1];
        const float v010 = p[256],   v011 = p[257];
        const float v100 = p[65536], v101 = p[65537];
        const float v110 = p[65792], v111 = p[65793];
        const float c00 = fmaf(fa, v001 - v000, v000);
        const float c01 = fmaf(fa, v011 - v010, v010);
        const float c10 = fmaf(fa, v101 - v100, v100);
        const float c11 = fmaf(fa, v111 - v110, v110);
        const float c0 = fmaf(fb, c01 - c00, c00);
        const float c1 = fmaf(fb, c11 - c10, c10);
        acc += fmaf(fc, c1 - c0, c0);
    }
    for (int s = sp.s1; s < sp.g1; ++s) {
        const float t = T0 + (s + 0.5f) * DT;
        acc += sample_shell(vol, fmaf(t, dx, bx), fmaf(t, dy, by), fmaf(t, dz, bz));
    }
    out[tid] = acc * DT;
}

// ---------- fallback B: plain fp32 -------------------------------------------
__global__ __launch_bounds__(256) void projector3d_f32_kernel(
    const float* __restrict__ vol, const float* __restrict__ angles,
    float* __restrict__ out)
{
    const int tid = blockIdx.x * 256 + threadIdx.x;
    const Spans sp = ray_setup(angles, tid);
    const float dx = sp.dx, dy = sp.dy, dz = sp.dz;
    const float bx = sp.bx, by = sp.by, bz = sp.bz;
    float acc = 0.0f;
    for (int s = sp.g0; s < sp.s0; ++s) {
        const float t = T0 + (s + 0.5f) * DT;
        acc += sample_shell(vol, fmaf(t, dx, bx), fmaf(t, dy, by), fmaf(t, dz, bz));
    }
    #pragma unroll 4
    for (int s = sp.s0; s < sp.s1; ++s) {
        const float t = T0 + (s + 0.5f) * DT;
        const float vx = fmaf(t, dx, bx), vy = fmaf(t, dy, by), vz = fmaf(t, dz, bz);
        const float fx0 = floorf(vx), fy0 = floorf(vy), fz0 = floorf(vz);
        const int x0 = (int)fx0, y0 = (int)fy0, z0 = (int)fz0;
        const float fx = vx - fx0, fy = vy - fy0, fz = vz - fz0;
        const float* p = vol + ((z0 << 16) | (y0 << 8) | x0);
        const float v000 = p[0],     v001 = p[1];
        const float v010 = p[256],   v011 = p[257];
        const float v100 = p[65536], v101 = p[65537];
        const float v110 = p[65792], v111 = p[65793];
        const float c00 = fmaf(fx, v001 - v000, v000);
        const float c01 = fmaf(fx, v011 - v010, v010);
        const float c10 = fmaf(fx, v101 - v100, v100);
        const float c11 = fmaf(fx, v111 - v110, v110);
        const float c0 = fmaf(fy, c01 - c00, c00);
        const float c1 = fmaf(fy, c11 - c10, c10);
        acc += fmaf(fz, c1 - c0, c0);
    }
    for (int s = sp.s1; s < sp.g1; ++s) {
        const float t = T0 + (s + 0.5f) * DT;
        acc += sample_shell(vol, fmaf(t, dx, bx), fmaf(t, dy, by), fmaf(t, dz, bz));
    }
    out[tid] = acc * DT;
}

extern "C" void kernel_launch(void* const* d_in, const int* in_sizes, int n_in,
                              void* d_out, int out_size, void* d_ws, size_t ws_size,
                              hipStream_t stream) {
    const float* vol    = (const float*)d_in[0];
    const float* angles = (const float*)d_in[1];
    float* out = (float*)d_out;

    const int grid = (NVIEW * NROW * NCOL) / 256;       // 1536
    if (ws_size >= 2u * VOL_N * sizeof(__half2)) {      // 134 MB: z-pair dual
        __half2* P  = (__half2*)d_ws;
        __half2* PT = P + VOL_N;
        dim3 tgrid(8, 8, 256), tblk(32, 8);
        packBoth_kernel<<<tgrid, tblk, 0, stream>>>(vol, P, PT);
        projector3d_zp_kernel<<<grid, 256, 0, stream>>>(vol, P, PT, angles, out);
    } else if (ws_size >= VOL_N * sizeof(float)) {      // 67 MB: dual-layout fp32
        float* volT = (float*)d_ws;
        dim3 tgrid(8, 8, 256), tblk(32, 8);
        transpose_kernel<<<tgrid, tblk, 0, stream>>>(vol, volT);
        projector3d_dual_kernel<<<grid, 256, 0, stream>>>(vol, volT, angles, out);
    } else {
        projector3d_f32_kernel<<<grid, 256, 0, stream>>>(vol, angles, out);
    }
}